// Round 2
// baseline (518.678 us; speedup 1.0000x reference)
//
#include <hip/hip_runtime.h>
#include <hip/hip_fp16.h>
#include <math.h>

#define BDIM 256
constexpr int Bb   = 8;
constexpr int C    = 512;
constexpr int T    = 4;
constexpr int HW   = 64 * 64;    // 4096
constexpr int NSP  = 100;
constexpr int DOUT = 128;
constexpr int PB   = 256;        // pixels per block (2 sub-tiles of 128)
constexpr int PSUB = 128;        // pixels per sub-tile (MFMA tile)
constexpr int KB   = 32;         // K chunk (channels per chunk)
constexpr int NCH  = C / KB;     // 16 chunks
constexpr int AST  = KB + 4;     // 36 halves: A-tile row stride (2-way-free reads)
constexpr int BST  = DOUT + 4;   // 132 f32: bins row stride (bank-spread scatter)
constexpr int PLANE = T * HW;    // 16384 floats between channels

typedef _Float16 f16;
typedef _Float16 f16x4 __attribute__((ext_vector_type(4)));
typedef _Float16 f16x8 __attribute__((ext_vector_type(8)));
typedef float    f32x4 __attribute__((ext_vector_type(4)));

// --------------- K0: zero the fp32 accumulator S (3200 x 128) ---------------
__global__ __launch_bounds__(BDIM) void zero_ws(float* __restrict__ S) {
    int i = blockIdx.x * BDIM + threadIdx.x;        // grid covers exactly 102400 f4
    ((float4*)S)[i] = float4{0.f, 0.f, 0.f, 0.f};
}

// ---- K1: fused FC (512->128, f16 MFMA) + segment-sum scatter over d=128 ----
// grid = 32 bt * 16 pixel-chunks = 512 blocks (2/CU), 4 waves (2x2).
// Each block processes 256 pixels as two 128-px sub-tiles sharing one bins[].
// A = maps^T staged to LDS as f16 [p][c] (stride 36, XOR-swizzled groups);
// B = W rows gathered from global (L2-resident), cvt to f16 in regs.
// Y[p][d] fragments scattered into bins[id[p]][d] with LDS float atomics;
// bins flushed DENSELY per touched row (64-lane 256B-coalesced global f32
// atomics) -> ~24 MB RMW traffic vs 247 MB for the sparse per-element flush.
// 1/cnt cancels in the final L2-normalize, so no counts are needed at all.
__global__ __launch_bounds__(BDIM, 2) void fc_scatter_kernel(
    const float* __restrict__ maps,   // (B,C,T,H,W) fp32
    const int*   __restrict__ mask,   // (B,T,H,W) int32
    const float* __restrict__ Wfc,    // (128, 512) fp32
    float*       __restrict__ S)      // (B*T*NSP, 128) fp32 accumulator
{
    __shared__ __half Al[PSUB * AST];   // 9216 B
    __shared__ float  bins[NSP * BST];  // 52800 B
    __shared__ int    ids[PB];          // 1024 B
    __shared__ int    touched[NSP];     // 400 B   (total ~63.4 KB -> 2/CU)

    const int tid = threadIdx.x;
    const int l   = tid & 63;
    const int wv  = tid >> 6;
    const int wp  = wv >> 1;          // p-half of sub-tile
    const int wd  = wv & 1;           // d-half
    const int lg  = l >> 4;           // k-group 0..3
    const int le  = l & 15;

    const int bid = blockIdx.x;
    const int pc  = bid & 15;         // pixel chunk (256 px each)
    const int bt  = bid >> 4;         // b*T + t
    const int b   = bt >> 2, t = bt & 3;
    const int p0  = pc * PB;

    for (int e = tid; e < NSP * BST; e += BDIM) bins[e] = 0.f;
    if (tid < NSP) touched[tid] = 0;
    __syncthreads();                  // init vs marking race

    // superpixel ids for all 256 pixels + touched flags
    int myid = mask[(size_t)bt * HW + p0 + tid];
    ids[tid] = myid;
    touched[myid] = 1;                // plain store, same-value race is fine

    const float* mbase = maps + ((size_t)b * C * T + t) * HW + p0;

    // ---- staging helpers (per 128-px sub-tile) ----
    // A: thread handles 2 (c-pair, p-quad) cells: pi=i*256+tid -> cp=pi>>5,
    // q=pi&31. Coalesced float4 loads along p; writes pack (c,c+1) into
    // __half2 at half2-slot cp ^ (((q>>2)&3)<<2) (XOR swizzle, ~2-way).
    float4 ra[2][4];
    auto loadA = [&](const float* mb, int kc, float4* r) {
        const int c0 = kc * KB;
#pragma unroll
        for (int i = 0; i < 2; i++) {
            int pi = i * BDIM + tid;
            int cp = pi >> 5, q = pi & 31;
            const float* src = mb + (size_t)(c0 + 2 * cp) * PLANE + 4 * q;
            r[2 * i]     = *(const float4*)src;
            r[2 * i + 1] = *(const float4*)(src + PLANE);
        }
    };
    auto storeA = [&](const float4* r) {
#pragma unroll
        for (int i = 0; i < 2; i++) {
            int pi = i * BDIM + tid;
            int cp = pi >> 5, q = pi & 31;
            int slot = cp ^ (((q >> 2) & 3) << 2);
#pragma unroll
            for (int j = 0; j < 4; j++) {
                __half2 h = __floats2half2_rn(((const float*)&r[2 * i])[j],
                                              ((const float*)&r[2 * i + 1])[j]);
                *(__half2*)&Al[(size_t)(4 * q + j) * AST + 2 * slot] = h;
            }
        }
    };

    // B: W rows gathered per lane (8 consecutive c = this lane's k-run)
    float4 rb[8];
    auto loadB = [&](int kc) {
        const int cb = kc * KB + 8 * lg;
#pragma unroll
        for (int dt = 0; dt < 4; dt++) {
            int d = wd * 64 + dt * 16 + le;
            const float* src = Wfc + (size_t)d * C + cb;
            rb[2 * dt]     = *(const float4*)src;
            rb[2 * dt + 1] = *(const float4*)(src + 4);
        }
    };
    f16x8 bf[4];
    auto cvtB = [&]() {
#pragma unroll
        for (int dt = 0; dt < 4; dt++) {
            f16x8 v;
#pragma unroll
            for (int j = 0; j < 4; j++) {
                v[j]     = (f16)((const float*)&rb[2 * dt])[j];
                v[j + 4] = (f16)((const float*)&rb[2 * dt + 1])[j];
            }
            bf[dt] = v;
        }
    };

    // ---- two 128-px sub-tiles; bins accumulate across both ----
    for (int half = 0; half < 2; half++) {
        const float* mb = mbase + half * PSUB;
        f32x4 acc[4][4] = {};             // [pt][dt]

        loadA(mb, 0, ra[0]);
        loadB(0);
        loadA(mb, 1, ra[1]);

        for (int kc = 0; kc < NCH; kc++) {
            storeA(ra[kc & 1]);
            if (kc + 2 < NCH) loadA(mb, kc + 2, ra[kc & 1]);
            cvtB();                        // consume rb (chunk kc)
            if (kc + 1 < NCH) loadB(kc + 1);
            __syncthreads();
#pragma unroll
            for (int pt = 0; pt < 4; pt++) {
                int p_loc = wp * 64 + pt * 16 + le;
                int g2 = lg ^ (pt & 3);    // undo write-side XOR swizzle
                const __half* ap = &Al[(size_t)p_loc * AST + 8 * g2];
                f16x4 a0 = *(const f16x4*)ap;
                f16x4 a1 = *(const f16x4*)(ap + 4);
                f16x8 af = __builtin_shufflevector(a0, a1, 0, 1, 2, 3, 4, 5, 6, 7);
#pragma unroll
                for (int dt = 0; dt < 4; dt++)
                    acc[pt][dt] = __builtin_amdgcn_mfma_f32_16x16x32_f16(
                        af, bf[dt], acc[pt][dt], 0, 0, 0);
            }
            __syncthreads();
        }

        // scatter Y fragments into bins: 16-lane groups add 16 consecutive d
        // (bank-spread by BST=132)
#pragma unroll
        for (int pt = 0; pt < 4; pt++) {
#pragma unroll
            for (int r = 0; r < 4; r++) {
                int p_loc = wp * 64 + pt * 16 + lg * 4 + r;  // C/D row mapping
                int n = ids[half * PSUB + p_loc];
                float* bp = &bins[n * BST + wd * 64 + le];   // C/D col mapping
#pragma unroll
                for (int dt = 0; dt < 4; dt++)
                    unsafeAtomicAdd(bp + dt * 16, acc[pt][dt][r]);
            }
        }
    }
    __syncthreads();

    // ---- flush: DENSE per touched row, 256B-coalesced global f32 atomics ----
    float* Srow = S + (size_t)bt * NSP * DOUT;
    for (int n = wv; n < NSP; n += 4) {
        if (touched[n]) {                  // wave-uniform gate
            const float* bp = &bins[n * BST];
            unsafeAtomicAdd(&Srow[n * DOUT + l],      bp[l]);
            unsafeAtomicAdd(&Srow[n * DOUT + 64 + l], bp[64 + l]);
        }
    }
}

// --------- K2: per-row L2 normalize (cnt cancels) + transpose store ---------
__global__ __launch_bounds__(BDIM) void norm_kernel(
    const float* __restrict__ S,      // (3200, 128)
    float*       __restrict__ out)    // (B, 128, T, NSP)
{
    const int tid = threadIdx.x, l = tid & 63, wv = tid >> 6;
    const int row = blockIdx.x * 4 + wv;              // 0..3199
    float v0 = S[(size_t)row * DOUT + l];
    float v1 = S[(size_t)row * DOUT + 64 + l];
    float ss = v0 * v0 + v1 * v1;
#pragma unroll
    for (int off = 32; off; off >>= 1) ss += __shfl_xor(ss, off, 64);
    float inv = 1.f / fmaxf(sqrtf(ss), 1e-12f);
    int n = row % NSP, bt = row / NSP;
    int b = bt >> 2, t = bt & 3;
    out[(((size_t)b * DOUT + l) * T + t) * NSP + n]      = v0 * inv;
    out[(((size_t)b * DOUT + l + 64) * T + t) * NSP + n] = v1 * inv;
}

extern "C" void kernel_launch(void* const* d_in, const int* in_sizes, int n_in,
                              void* d_out, int out_size, void* d_ws, size_t ws_size,
                              hipStream_t stream) {
    // Identify inputs by SIZE RANK (robust to ordering):
    // maps (67.1M el) > sp_mask (131K el) > W_fc (65.5K el) > scalar (1).
    int iMaps = 0, iMask = 1, iW = 2;
    {
        long best = -1;
        for (int i = 0; i < n_in; i++)
            if ((long)in_sizes[i] > best) { best = in_sizes[i]; iMaps = i; }
        long b2 = -1;
        for (int i = 0; i < n_in; i++)
            if (i != iMaps && (long)in_sizes[i] > b2) { b2 = in_sizes[i]; iMask = i; }
        long b3 = -1;
        for (int i = 0; i < n_in; i++)
            if (i != iMaps && i != iMask && (long)in_sizes[i] > b3) { b3 = in_sizes[i]; iW = i; }
    }
    const float* maps = (const float*)d_in[iMaps];  // fp32
    const int*   mask = (const int*)d_in[iMask];    // int32
    const float* Wfc  = (const float*)d_in[iW];     // fp32
    float*       out  = (float*)d_out;              // fp32
    float*       S    = (float*)d_ws;               // 3200*128 fp32 = 1.64 MB

    const dim3 blk(BDIM);
    // K0: 3200*128 floats = 102400 float4 = 400 * 256
    zero_ws<<<dim3(400), blk, 0, stream>>>(S);
    // K1: 32 bt * 16 pixel-chunks (256 px each)
    fc_scatter_kernel<<<dim3(Bb * T * (HW / PB)), blk, 0, stream>>>(maps, mask, Wfc, S);
    // K2: 3200 rows / 4 rows-per-block
    norm_kernel<<<dim3(Bb * T * NSP / 4), blk, 0, stream>>>(S, out);
}

// Round 3
// 509.368 us; speedup vs baseline: 1.0183x; 1.0183x over previous
//
#include <hip/hip_runtime.h>
#include <hip/hip_fp16.h>
#include <math.h>

#define BDIM 256
constexpr int Bb   = 8;
constexpr int C    = 512;
constexpr int T    = 4;
constexpr int HW   = 64 * 64;    // 4096
constexpr int NSP  = 100;
constexpr int DOUT = 128;
constexpr int PB   = 256;        // pixels per block (2 sub-tiles of 128)
constexpr int PSUB = 128;        // pixels per sub-tile (MFMA tile)
constexpr int KB   = 32;         // K chunk (channels per chunk)
constexpr int NCH  = C / KB;     // 16 chunks
constexpr int AST  = KB + 4;     // 36 halves: A-tile row stride (2-way-free reads)
constexpr int PLANE = T * HW;    // 16384 floats between channels

typedef _Float16 f16;
typedef _Float16 f16x4 __attribute__((ext_vector_type(4)));
typedef _Float16 f16x8 __attribute__((ext_vector_type(8)));
typedef float    f32x4 __attribute__((ext_vector_type(4)));

// --------------- K0: zero the fp32 accumulator S (3200 x 128) ---------------
__global__ __launch_bounds__(BDIM) void zero_ws(float* __restrict__ S) {
    int i = blockIdx.x * BDIM + threadIdx.x;        // grid covers exactly 102400 f4
    ((float4*)S)[i] = float4{0.f, 0.f, 0.f, 0.f};
}

// ---- K1: fused FC (512->128, f16 MFMA) + one-hot-MFMA segment sum ----------
// grid = 32 bt * 16 pixel-chunks = 512 blocks (2/CU), 4 waves (2x2).
// Per 128-px half:
//   phase 1: Y[p][d] = maps^T . W  (f16 MFMA, f32 acc)   [as rounds 1-2]
//   phase 2: Y -> LDS Ylt[d][p] (f16, 16B-slot XOR swizzle: slot^= d&15)
//   phase 3: bins[n][d] += onehot(ids)[n][p] . Y[p][d]  -- one-hot A-frags
//            built IN REGISTERS from ids (cmp/select), B-frags are single
//            conflict-free ds_read_b128 from Ylt. Bins live in 64 VGPRs.
// This removes ALL 16.8M LDS scatter atomics (measured ~85us of LDS-pipe
// serialization at ~3.1 cyc/lane-atomic, calibrated on round-0's kernel).
// Flush: unchanged round-2 dense touched-gated global f32 atomics (isolates
// flush cost in next profile). 1/cnt still cancels in the final normalize.
__global__ __launch_bounds__(BDIM, 2) void fc_scatter_kernel(
    const float* __restrict__ maps,   // (B,C,T,H,W) fp32
    const int*   __restrict__ mask,   // (B,T,H,W) int32
    const float* __restrict__ Wfc,    // (128, 512) fp32
    float*       __restrict__ S)      // (B*T*NSP, 128) fp32 accumulator
{
    __shared__ __half Al[PSUB * AST];            // 9216 B
    __shared__ f16    Ylt[DOUT * PSUB];          // 32 KB: [d][p], swizzled slots
    __shared__ alignas(16) int ids[PB];          // 1024 B
    __shared__ int    touched[NSP];              // 400 B   (~43 KB total)

    const int tid = threadIdx.x;
    const int l   = tid & 63;
    const int wv  = tid >> 6;
    const int wp  = wv >> 1;          // p-half (phase1) / n-half (phase3)
    const int wd  = wv & 1;           // d-half (both GEMMs)
    const int lg  = l >> 4;           // k-group 0..3
    const int le  = l & 15;

    const int bid = blockIdx.x;
    const int pc  = bid & 15;         // pixel chunk (256 px each)
    const int bt  = bid >> 4;         // b*T + t
    const int b   = bt >> 2, t = bt & 3;
    const int p0  = pc * PB;

    if (tid < NSP) touched[tid] = 0;
    __syncthreads();                  // init vs marking race

    int myid = mask[(size_t)bt * HW + p0 + tid];
    ids[tid] = myid;
    touched[myid] = 1;                // same-value race is fine

    const float* mbase = maps + ((size_t)b * C * T + t) * HW + p0;

    // ---- phase-1 staging helpers (per 128-px sub-tile), as rounds 1-2 ----
    float4 ra[2][4];
    auto loadA = [&](const float* mb, int kc, float4* r) {
        const int c0 = kc * KB;
#pragma unroll
        for (int i = 0; i < 2; i++) {
            int pi = i * BDIM + tid;
            int cp = pi >> 5, q = pi & 31;
            const float* src = mb + (size_t)(c0 + 2 * cp) * PLANE + 4 * q;
            r[2 * i]     = *(const float4*)src;
            r[2 * i + 1] = *(const float4*)(src + PLANE);
        }
    };
    auto storeA = [&](const float4* r) {
#pragma unroll
        for (int i = 0; i < 2; i++) {
            int pi = i * BDIM + tid;
            int cp = pi >> 5, q = pi & 31;
            int slot = cp ^ (((q >> 2) & 3) << 2);
#pragma unroll
            for (int j = 0; j < 4; j++) {
                __half2 h = __floats2half2_rn(((const float*)&r[2 * i])[j],
                                              ((const float*)&r[2 * i + 1])[j]);
                *(__half2*)&Al[(size_t)(4 * q + j) * AST + 2 * slot] = h;
            }
        }
    };

    float4 rb[8];
    auto loadB = [&](int kc) {
        const int cb = kc * KB + 8 * lg;
#pragma unroll
        for (int dt = 0; dt < 4; dt++) {
            int d = wd * 64 + dt * 16 + le;
            const float* src = Wfc + (size_t)d * C + cb;
            rb[2 * dt]     = *(const float4*)src;
            rb[2 * dt + 1] = *(const float4*)(src + 4);
        }
    };
    f16x8 bf[4];
    auto cvtB = [&]() {
#pragma unroll
        for (int dt = 0; dt < 4; dt++) {
            f16x8 v;
#pragma unroll
            for (int j = 0; j < 4; j++) {
                v[j]     = (f16)((const float*)&rb[2 * dt])[j];
                v[j + 4] = (f16)((const float*)&rb[2 * dt + 1])[j];
            }
            bf[dt] = v;
        }
    };

    f32x4 bins[4][4] = {};            // [nt][dt] persistent across halves

    // ---- two 128-px sub-tiles ----
    for (int half = 0; half < 2; half++) {
        const float* mb = mbase + half * PSUB;
        f32x4 acc[4][4] = {};         // [pt][dt]

        loadA(mb, 0, ra[0]);
        loadB(0);
        loadA(mb, 1, ra[1]);

        for (int kc = 0; kc < NCH; kc++) {
            storeA(ra[kc & 1]);
            if (kc + 2 < NCH) loadA(mb, kc + 2, ra[kc & 1]);
            cvtB();
            if (kc + 1 < NCH) loadB(kc + 1);
            __syncthreads();
#pragma unroll
            for (int pt = 0; pt < 4; pt++) {
                int p_loc = wp * 64 + pt * 16 + le;
                int g2 = lg ^ (pt & 3);
                const __half* ap = &Al[(size_t)p_loc * AST + 8 * g2];
                f16x4 a0 = *(const f16x4*)ap;
                f16x4 a1 = *(const f16x4*)(ap + 4);
                f16x8 af = __builtin_shufflevector(a0, a1, 0, 1, 2, 3, 4, 5, 6, 7);
#pragma unroll
                for (int dt = 0; dt < 4; dt++)
                    acc[pt][dt] = __builtin_amdgcn_mfma_f32_16x16x32_f16(
                        af, bf[dt], acc[pt][dt], 0, 0, 0);
            }
            __syncthreads();
        }
        // all waves past last barrier -> Ylt reads of previous half are done

        // ---- phase 2: acc -> Ylt[d][p] (f16), 16B-slot XOR swizzle ----
        // D-frag: row p = wp*64+pt*16+lg*4+r, col d = wd*64+dt*16+le.
        // 4 consecutive r share one 8B slot-segment -> single f16x4 write.
#pragma unroll
        for (int pt = 0; pt < 4; pt++) {
            int pb4 = wp * 64 + pt * 16 + lg * 4;   // p of r=0
#pragma unroll
            for (int dt = 0; dt < 4; dt++) {
                int d = wd * 64 + dt * 16 + le;
                f16x4 v;
#pragma unroll
                for (int r = 0; r < 4; r++) v[r] = (f16)acc[pt][dt][r];
                int slot = (pb4 >> 3) ^ (d & 15);
                *(f16x4*)&Ylt[d * PSUB + slot * 8 + (pb4 & 7)] = v;
            }
        }
        __syncthreads();

        // ---- phase 3: bins += onehot . Y  (A-frags from regs, B from Ylt) ----
#pragma unroll
        for (int kt = 0; kt < 4; kt++) {
            // this lane's 8 pixel ids for A-frag k-run
            int pbase = half * PSUB + kt * 32 + lg * 8;
            int4 i0 = *(const int4*)&ids[pbase];
            int4 i1 = *(const int4*)&ids[pbase + 4];
            int idv[8] = {i0.x, i0.y, i0.z, i0.w, i1.x, i1.y, i1.z, i1.w};
            // B-frags: 8 consecutive p at column d -> one b128 each
            f16x8 yb[4];
#pragma unroll
            for (int dt = 0; dt < 4; dt++) {
                int d = wd * 64 + dt * 16 + le;
                int slotB = (kt * 4 + lg) ^ (d & 15);
                yb[dt] = *(const f16x8*)&Ylt[d * PSUB + slotB * 8];
            }
#pragma unroll
            for (int nt = 0; nt < 4; nt++) {
                int n = wp * 64 + nt * 16 + le;
                f16x8 af;
#pragma unroll
                for (int j = 0; j < 8; j++)
                    af[j] = (idv[j] == n) ? (f16)1.0f : (f16)0.0f;
#pragma unroll
                for (int dt = 0; dt < 4; dt++)
                    bins[nt][dt] = __builtin_amdgcn_mfma_f32_16x16x32_f16(
                        af, yb[dt], bins[nt][dt], 0, 0, 0);
            }
        }
        __syncthreads();   // Ylt consumed; next half may rewrite
    }

    // ---- flush: dense touched-gated global f32 atomics (round-2 pattern) ----
    // bins D-frag: row n = wp*64+nt*16+lg*4+r, col d = wd*64+dt*16+le
    float* Srow = S + (size_t)bt * NSP * DOUT;
#pragma unroll
    for (int nt = 0; nt < 4; nt++) {
#pragma unroll
        for (int r = 0; r < 4; r++) {
            int n = wp * 64 + nt * 16 + lg * 4 + r;
            if (n < NSP && touched[n]) {
                float* bp = &Srow[n * DOUT + wd * 64 + le];
#pragma unroll
                for (int dt = 0; dt < 4; dt++)
                    unsafeAtomicAdd(bp + dt * 16, bins[nt][dt][r]);
            }
        }
    }
}

// --------- K2: per-row L2 normalize (cnt cancels) + transpose store ---------
__global__ __launch_bounds__(BDIM) void norm_kernel(
    const float* __restrict__ S,      // (3200, 128)
    float*       __restrict__ out)    // (B, 128, T, NSP)
{
    const int tid = threadIdx.x, l = tid & 63, wv = tid >> 6;
    const int row = blockIdx.x * 4 + wv;              // 0..3199
    float v0 = S[(size_t)row * DOUT + l];
    float v1 = S[(size_t)row * DOUT + 64 + l];
    float ss = v0 * v0 + v1 * v1;
#pragma unroll
    for (int off = 32; off; off >>= 1) ss += __shfl_xor(ss, off, 64);
    float inv = 1.f / fmaxf(sqrtf(ss), 1e-12f);
    int n = row % NSP, bt = row / NSP;
    int b = bt >> 2, t = bt & 3;
    out[(((size_t)b * DOUT + l) * T + t) * NSP + n]      = v0 * inv;
    out[(((size_t)b * DOUT + l + 64) * T + t) * NSP + n] = v1 * inv;
}

extern "C" void kernel_launch(void* const* d_in, const int* in_sizes, int n_in,
                              void* d_out, int out_size, void* d_ws, size_t ws_size,
                              hipStream_t stream) {
    // Identify inputs by SIZE RANK (robust to ordering):
    // maps (67.1M el) > sp_mask (131K el) > W_fc (65.5K el) > scalar (1).
    int iMaps = 0, iMask = 1, iW = 2;
    {
        long best = -1;
        for (int i = 0; i < n_in; i++)
            if ((long)in_sizes[i] > best) { best = in_sizes[i]; iMaps = i; }
        long b2 = -1;
        for (int i = 0; i < n_in; i++)
            if (i != iMaps && (long)in_sizes[i] > b2) { b2 = in_sizes[i]; iMask = i; }
        long b3 = -1;
        for (int i = 0; i < n_in; i++)
            if (i != iMaps && i != iMask && (long)in_sizes[i] > b3) { b3 = in_sizes[i]; iW = i; }
    }
    const float* maps = (const float*)d_in[iMaps];  // fp32
    const int*   mask = (const int*)d_in[iMask];    // int32
    const float* Wfc  = (const float*)d_in[iW];     // fp32
    float*       out  = (float*)d_out;              // fp32
    float*       S    = (float*)d_ws;               // 3200*128 fp32 = 1.64 MB

    const dim3 blk(BDIM);
    // K0: 3200*128 floats = 102400 float4 = 400 * 256
    zero_ws<<<dim3(400), blk, 0, stream>>>(S);
    // K1: 32 bt * 16 pixel-chunks (256 px each)
    fc_scatter_kernel<<<dim3(Bb * T * (HW / PB)), blk, 0, stream>>>(maps, mask, Wfc, S);
    // K2: 3200 rows / 4 rows-per-block
    norm_kernel<<<dim3(Bb * T * NSP / 4), blk, 0, stream>>>(S, out);
}

// Round 4
// 372.906 us; speedup vs baseline: 1.3909x; 1.3659x over previous
//
#include <hip/hip_runtime.h>
#include <hip/hip_fp16.h>
#include <math.h>

#define BDIM 512
constexpr int Bb   = 8;
constexpr int C    = 512;
constexpr int T    = 4;
constexpr int HW   = 64 * 64;    // 4096
constexpr int NSP  = 100;
constexpr int DOUT = 128;
constexpr int PB   = 512;        // pixels per block
constexpr int KB   = 32;         // K chunk (channels per chunk)
constexpr int NCH  = C / KB;     // 16 chunks
constexpr int AST  = 36;         // halves per Al row (512 rows)
constexpr int WST  = 40;         // halves per Ws row (80B, 16B-aligned)
constexpr int PLANE = T * HW;    // 16384 floats between channels

typedef _Float16 f16;
typedef _Float16 f16x4 __attribute__((ext_vector_type(4)));
typedef _Float16 f16x8 __attribute__((ext_vector_type(8)));
typedef float    f32x4 __attribute__((ext_vector_type(4)));

// --------------- K0: zero the fp32 accumulator S (3200 x 128) ---------------
__global__ __launch_bounds__(256) void zero_ws(float* __restrict__ S) {
    int i = blockIdx.x * 256 + threadIdx.x;         // grid covers exactly 102400 f4
    ((float4*)S)[i] = float4{0.f, 0.f, 0.f, 0.f};
}

// ---- K1: fused FC (512->128, f16 MFMA) + one-hot-MFMA segment sum ----------
// ROUND-4 CHANGE: all three prior rounds read maps as 512B segments at 64KB
// stride and all pinned at ~1.05 TB/s effective -> memory-PATTERN-bound.
// This version stages A as [512px][32c] per K-chunk so each channel is read
// as a 2KB-contiguous span (4x granularity). grid = 32 bt * 8 px-chunks =
// 256 blocks (1/CU), BDIM=512 (8 waves), each wave owns 64px x 128d
// (acc = 128 VGPR). W staged per-kc into LDS (Ws[d][c], padded).
// Phase 2/3 = round-3's verified Ylt + one-hot MFMA, per 128-px chunk.
// Flush: dense touched-gated global f32 atomics, 3.3M lanes total.
__global__ __launch_bounds__(BDIM, 2) void fc_scatter_kernel(
    const float* __restrict__ maps,   // (B,C,T,H,W) fp32
    const int*   __restrict__ mask,   // (B,T,H,W) int32
    const float* __restrict__ Wfc,    // (128, 512) fp32
    float*       __restrict__ S)      // (B*T*NSP, 128) fp32 accumulator
{
    // Al (36864B) and Ylt (32768B) are temporally disjoint -> union
    __shared__ alignas(16) char shraw[PB * AST * 2];
    __half* Al  = (__half*)shraw;                // [512 px][AST halves]
    f16*    Ylt = (f16*)shraw;                   // [128 d][128 p] per chunk
    __shared__ __half Ws[DOUT * WST];            // 10240B, [d][c-run] f16
    __shared__ alignas(16) int ids[PB];          // 2048B
    __shared__ int touched[NSP];                 // 400B   (~49.6 KB total)

    const int tid = threadIdx.x;
    const int l   = tid & 63;
    const int wv  = tid >> 6;         // 0..7: px-octant in phase 1
    const int lg  = l >> 4;           // k-group 0..3
    const int le  = l & 15;

    const int bid = blockIdx.x;
    const int pc  = bid & 7;          // pixel chunk (512 px each)
    const int bt  = bid >> 3;         // b*T + t
    const int b   = bt >> 2, t = bt & 3;
    const int p0  = pc * PB;

    if (tid < NSP) touched[tid] = 0;
    __syncthreads();                  // init vs marking race

    int myid = mask[(size_t)bt * HW + p0 + tid];
    ids[tid] = myid;
    touched[myid] = 1;                // same-value race is fine

    const float* mbase = maps + ((size_t)b * C * T + t) * HW + p0;

    // ---- staging: A as [512px][32c] per kc; per-channel read = 2KB contig ---
    // wave wv owns channels 4wv..4wv+3; i-loop: c = 4wv + (i>>1), half h = i&1.
    // Each wave-instr: 64 lanes x 16B = 1KB contiguous; h=0,1 consecutive.
    float4 ra[8];
    auto loadA = [&](int kc) {
#pragma unroll
        for (int i = 0; i < 8; i++) {
            int c = kc * KB + 4 * wv + (i >> 1);
            int h = i & 1;
            ra[i] = *(const float4*)(mbase + (size_t)c * PLANE + h * 256 + 4 * l);
        }
    };
    // pack (c,c+1) half2 at slot = cp ^ (((px>>4)&3)<<2)  (round-3 swizzle)
    auto storeA = [&]() {
#pragma unroll
        for (int j = 0; j < 2; j++) {
#pragma unroll
            for (int h = 0; h < 2; h++) {
                const float* lo = (const float*)&ra[4 * j + h];      // c = 4wv+2j
                const float* hi = (const float*)&ra[4 * j + 2 + h];  // c+1
                int cp = 2 * wv + j;                                 // 0..15
#pragma unroll
                for (int jj = 0; jj < 4; jj++) {
                    int px   = h * 256 + 4 * l + jj;
                    int slot = cp ^ (((px >> 4) & 3) << 2);
                    *(__half2*)&Al[px * AST + 2 * slot] =
                        __floats2half2_rn(lo[jj], hi[jj]);
                }
            }
        }
    };
    // W chunk -> LDS: thread covers (d = tid>>2, c-run = (tid&3)*8), one b128
    auto stageWs = [&](int kc) {
        int d = tid >> 2, cq = tid & 3;
        const float* src = Wfc + (size_t)d * C + kc * KB + cq * 8;
        float4 w0 = *(const float4*)src;
        float4 w1 = *(const float4*)(src + 4);
        f16x8 v;
        v[0] = (f16)w0.x; v[1] = (f16)w0.y; v[2] = (f16)w0.z; v[3] = (f16)w0.w;
        v[4] = (f16)w1.x; v[5] = (f16)w1.y; v[6] = (f16)w1.z; v[7] = (f16)w1.w;
        *(f16x8*)&Ws[d * WST + cq * 8] = v;
    };

    // ---- phase 1: Y[p][d] = A.W, acc[pt][dt] = wave's 64px x 128d ----------
    f32x4 acc[4][8] = {};
    loadA(0);
    for (int kc = 0; kc < NCH; kc++) {
        storeA();                     // waits on ra (kc) loads
        stageWs(kc);
        __syncthreads();
        if (kc + 1 < NCH) loadA(kc + 1);   // overlap next-chunk HBM with MFMA
#pragma unroll
        for (int dp = 0; dp < 2; dp++) {
            f16x8 bf[4];
#pragma unroll
            for (int m = 0; m < 4; m++) {
                int d = dp * 64 + m * 16 + le;
                bf[m] = *(const f16x8*)&Ws[d * WST + 8 * lg];
            }
#pragma unroll
            for (int pt = 0; pt < 4; pt++) {
                int p_loc = wv * 64 + pt * 16 + le;
                int g2 = lg ^ (pt & 3);      // undo write-side XOR swizzle
                const __half* ap = &Al[p_loc * AST + 8 * g2];
                f16x4 a0 = *(const f16x4*)ap;
                f16x4 a1 = *(const f16x4*)(ap + 4);
                f16x8 af = __builtin_shufflevector(a0, a1, 0, 1, 2, 3, 4, 5, 6, 7);
#pragma unroll
                for (int m = 0; m < 4; m++)
                    acc[pt][dp * 4 + m] = __builtin_amdgcn_mfma_f32_16x16x32_f16(
                        af, bf[m], acc[pt][dp * 4 + m], 0, 0, 0);
            }
        }
        __syncthreads();
    }

    // ---- phases 2+3 per 128-px chunk: Y->Ylt (f16), bins += onehot . Y -----
    // phase-3 wave roles: d-half = wv&1, n-half = (wv>>1)&1, nt-pair = wv>>2
    f32x4 bins[2][4] = {};            // [nt-local][dt3]
    const int dh3 = wv & 1, nh3 = (wv >> 1) & 1, rep = wv >> 2;

    for (int ch = 0; ch < 4; ch++) {
        if ((wv >> 1) == ch) {        // wave-uniform: octants 2ch, 2ch+1 write
            int pb0 = (wv & 1) * 64;  // local p-half within chunk
#pragma unroll
            for (int pt = 0; pt < 4; pt++) {
                int pb4 = pb0 + pt * 16 + lg * 4;
#pragma unroll
                for (int dt = 0; dt < 8; dt++) {
                    int d = dt * 16 + le;
                    f16x4 v;
#pragma unroll
                    for (int r = 0; r < 4; r++) v[r] = (f16)acc[pt][dt][r];
                    int slot = (pb4 >> 3) ^ (d & 15);
                    *(f16x4*)&Ylt[d * 128 + slot * 8 + (pb4 & 7)] = v;
                }
            }
        }
        __syncthreads();
#pragma unroll
        for (int kt = 0; kt < 4; kt++) {
            int pbase = ch * 128 + kt * 32 + lg * 8;
            int4 i0 = *(const int4*)&ids[pbase];
            int4 i1 = *(const int4*)&ids[pbase + 4];
            int idv[8] = {i0.x, i0.y, i0.z, i0.w, i1.x, i1.y, i1.z, i1.w};
            f16x8 yb[4];
#pragma unroll
            for (int m = 0; m < 4; m++) {
                int d = dh3 * 64 + m * 16 + le;
                int slotB = (kt * 4 + lg) ^ (d & 15);
                yb[m] = *(const f16x8*)&Ylt[d * 128 + slotB * 8];
            }
#pragma unroll
            for (int q = 0; q < 2; q++) {
                int n = nh3 * 64 + (rep * 2 + q) * 16 + le;
                f16x8 af;
#pragma unroll
                for (int j = 0; j < 8; j++)
                    af[j] = (idv[j] == n) ? (f16)1.0f : (f16)0.0f;
#pragma unroll
                for (int m = 0; m < 4; m++)
                    bins[q][m] = __builtin_amdgcn_mfma_f32_16x16x32_f16(
                        af, yb[m], bins[q][m], 0, 0, 0);
            }
        }
        __syncthreads();              // Ylt consumed; next chunk may rewrite
    }

    // ---- flush: dense touched-gated global f32 atomics (3.3M lanes total) --
    float* Srow = S + (size_t)bt * NSP * DOUT;
#pragma unroll
    for (int q = 0; q < 2; q++) {
#pragma unroll
        for (int r = 0; r < 4; r++) {
            int n = nh3 * 64 + (rep * 2 + q) * 16 + lg * 4 + r;
            if (n < NSP && touched[n]) {
                float* bp = &Srow[n * DOUT + dh3 * 64 + le];
#pragma unroll
                for (int m = 0; m < 4; m++)
                    unsafeAtomicAdd(bp + m * 16, bins[q][m][r]);
            }
        }
    }
}

// --------- K2: per-row L2 normalize (cnt cancels) + transpose store ---------
__global__ __launch_bounds__(256) void norm_kernel(
    const float* __restrict__ S,      // (3200, 128)
    float*       __restrict__ out)    // (B, 128, T, NSP)
{
    const int tid = threadIdx.x, l = tid & 63, wv = tid >> 6;
    const int row = blockIdx.x * 4 + wv;              // 0..3199
    float v0 = S[(size_t)row * DOUT + l];
    float v1 = S[(size_t)row * DOUT + 64 + l];
    float ss = v0 * v0 + v1 * v1;
#pragma unroll
    for (int off = 32; off; off >>= 1) ss += __shfl_xor(ss, off, 64);
    float inv = 1.f / fmaxf(sqrtf(ss), 1e-12f);
    int n = row % NSP, bt = row / NSP;
    int b = bt >> 2, t = bt & 3;
    out[(((size_t)b * DOUT + l) * T + t) * NSP + n]      = v0 * inv;
    out[(((size_t)b * DOUT + l + 64) * T + t) * NSP + n] = v1 * inv;
}

extern "C" void kernel_launch(void* const* d_in, const int* in_sizes, int n_in,
                              void* d_out, int out_size, void* d_ws, size_t ws_size,
                              hipStream_t stream) {
    // Identify inputs by SIZE RANK (robust to ordering):
    // maps (67.1M el) > sp_mask (131K el) > W_fc (65.5K el) > scalar (1).
    int iMaps = 0, iMask = 1, iW = 2;
    {
        long best = -1;
        for (int i = 0; i < n_in; i++)
            if ((long)in_sizes[i] > best) { best = in_sizes[i]; iMaps = i; }
        long b2 = -1;
        for (int i = 0; i < n_in; i++)
            if (i != iMaps && (long)in_sizes[i] > b2) { b2 = in_sizes[i]; iMask = i; }
        long b3 = -1;
        for (int i = 0; i < n_in; i++)
            if (i != iMaps && i != iMask && (long)in_sizes[i] > b3) { b3 = in_sizes[i]; iW = i; }
    }
    const float* maps = (const float*)d_in[iMaps];  // fp32
    const int*   mask = (const int*)d_in[iMask];    // int32
    const float* Wfc  = (const float*)d_in[iW];     // fp32
    float*       out  = (float*)d_out;              // fp32
    float*       S    = (float*)d_ws;               // 3200*128 fp32 = 1.64 MB

    // K0: 3200*128 floats = 102400 float4 = 400 * 256
    zero_ws<<<dim3(400), dim3(256), 0, stream>>>(S);
    // K1: 32 bt * 8 pixel-chunks (512 px each) = 256 blocks (1/CU)
    fc_scatter_kernel<<<dim3(Bb * T * (HW / PB)), dim3(BDIM), 0, stream>>>(
        maps, mask, Wfc, S);
    // K2: 3200 rows / 4 rows-per-block
    norm_kernel<<<dim3(Bb * T * NSP / 4), dim3(256), 0, stream>>>(S, out);
}